// Round 5
// baseline (135.087 us; speedup 1.0000x reference)
//
#include <hip/hip_runtime.h>
#include <cstdint>
#include <utility>

#define NW 10
#define NL 4

// ============================================================================
// Round 5:
//  - CNOT rings tracked as compile-time GF(2) index maps (round 2).
//  - Lightcone: layer3 keeps Rot{1,5,9}, layer2 drops Rot(7) (round 2).
//  - Product-state init folds encoding RYs + all layer-0 Rots (round 3).
//  - Cross-lane exchange via immediate ds_swizzle / ds_bpermute (round 4).
//  - NEW: state packed as v2 float (slots j and j+8 share one <2 x float>),
//    gate core uses v_pk_fma_f32 (packed fp32, full rate on CDNA4) -> the
//    2816 scalar FMAs/lane become 1408 VOP3P ops. Per-half compile-time
//    sign patterns land in neg_lo/neg_hi modifiers.
// ============================================================================

typedef float v2 __attribute__((ext_vector_type(2)));

struct Plan {
    int n;
    uint16_t pmask[40];
    uint16_t rmask[40];
    uint8_t  lw[40];
    uint16_t measmask;
};

constexpr bool keep_rot(int l, int w) {
    if (l <= 1) return true;
    if (l == 2) return w != 7;
    return w == 1 || w == 5 || w == 9;   // l == 3
}

constexpr Plan make_plan() {
    Plan P{};
    unsigned row[10], cI[10];
    for (int b = 0; b < 10; ++b) { row[b] = 1u << b; cI[b] = 1u << b; }
    P.n = 0;
    for (int l = 0; l < NL; ++l) {
        for (int w = 0; w < NW; ++w) {
            if (l > 0 && keep_rot(l, w)) {          // layer-0 Rots folded into init
                const int b = 9 - w;                // wire w = state bit 9-w
                P.pmask[P.n] = (uint16_t)cI[b];
                P.rmask[P.n] = (uint16_t)row[b];
                P.lw[P.n]    = (uint8_t)(l * NW + w);
                P.n++;
            }
        }
        const int r = l % (NW - 1) + 1;
        for (int w = 0; w < NW; ++w) {              // ring: CNOT(w, (w+r)%10)
            const int cb = 9 - w, tb = 9 - ((w + r) % NW);
            row[tb] ^= row[cb];                     // M <- C * M
            cI[cb]  ^= cI[tb];                      // Minv <- Minv * C
        }
    }
    P.measmask = (uint16_t)row[0];                  // Z on virtual bit 0 (wire 9)
    return P;
}

constexpr Plan PL = make_plan();
constexpr int NROT = 22;
static_assert(PL.n == NROT, "plan size mismatch");

__device__ __forceinline__ v2 mkv2(float a, float b) { v2 r; r.x = a; r.y = b; return r; }

// cross-lane xor exchange on one 32-bit value
template<int MASK>
__device__ __forceinline__ float swz(float v, int lane4 /* lane<<2 */) {
    if constexpr (MASK < 32) {
        return __int_as_float(__builtin_amdgcn_ds_swizzle(
            __float_as_int(v), (MASK << 10) | 0x1F));       // bit-mode xor pattern
    } else {
        return __int_as_float(__builtin_amdgcn_ds_bpermute(
            lane4 ^ (MASK << 2), __float_as_int(v)));
    }
}

// build packed partner (PR,PI) from a source pair's regs; pswap = pLoc bit3
template<int pLane, bool pswap>
__device__ __forceinline__ void mk_partner(v2 qr, v2 qi, v2& PR, v2& PI, int lane4) {
    if constexpr (pLane != 0) {
        const float rx = swz<pLane>(qr.x, lane4);
        const float ry = swz<pLane>(qr.y, lane4);
        const float ix = swz<pLane>(qi.x, lane4);
        const float iy = swz<pLane>(qi.y, lane4);
        if constexpr (pswap) { PR = mkv2(ry, rx); PI = mkv2(iy, ix); }
        else                 { PR = mkv2(rx, ry); PI = mkv2(ix, iy); }
    } else {
        if constexpr (pswap) { PR = mkv2(qr.y, qr.x); PI = mkv2(qi.y, qi.x); }
        else                 { PR = qr;               PI = qi;               }
    }
}

// packed rotation core: out = U * (X, P) with per-half signs already in eb/eo
__device__ __forceinline__ void pair_update(v2& OR_, v2& OI_, v2 XR, v2 XI, v2 PR, v2 PI,
                                            v2 cmr2, v2 coi2, v2 eb, v2 eo) {
    OR_ = cmr2 * XR - coi2 * PI - eb * XI + eo * PR;
    OI_ = cmr2 * XI + coi2 * PR + eb * XR + eo * PI;
}

__device__ __forceinline__ void cmul(float ar, float ai, float br, float bi,
                                     float& cr, float& ci) {
    cr = ar * br - ai * bi;
    ci = ar * bi + ai * br;
}

// one masked-pair rotation; SU(2): u11=conj(u00), u10=-conj(u01).
// state: SR[u]/SI[u] hold slots (u, u|8) packed.
template<int G>
__device__ __forceinline__ void apply_rot(v2 (&SR)[8], v2 (&SI)[8],
                                          const float4* __restrict__ rotm,
                                          int lane, int lane4) {
    constexpr unsigned pm = PL.pmask[G], rm = PL.rmask[G];
    constexpr int pLoc = pm & 15, pLane = (int)(pm >> 4);
    constexpr int rLoc = rm & 15, rLane = (int)(rm >> 4);
    constexpr bool pswap = (pLoc & 8) != 0;
    constexpr int  px    = pLoc & 7;
    constexpr bool mixed = (rLoc & 8) != 0;        // halves of a pair differ in role

    const float4 m = rotm[PL.lw[G]];
    const bool rl = (__popc(lane & rLane) & 1) != 0;   // runtime lane role
    const float bmi = rl ? -m.y : m.y;
    const float bor = rl ? -m.z : m.z;
    const v2 cmr2 = mkv2(m.x, m.x);
    const v2 coi2 = mkv2(m.w, m.w);
    const v2 bmi2 = mixed ? mkv2(bmi, -bmi) : mkv2(bmi, bmi);
    const v2 bor2 = mixed ? mkv2(bor, -bor) : mkv2(bor, bor);

    if constexpr (px == 0) {
        // partner lives in the same packed pair (other lane and/or other half)
#pragma unroll
        for (int u = 0; u < 8; ++u) {
            v2 PR, PI;
            mk_partner<pLane, pswap>(SR[u], SI[u], PR, PI, lane4);
            const bool s0 = (__builtin_popcount(u & rLoc) & 1) != 0;
            const v2 eb = s0 ? -bmi2 : bmi2;
            const v2 eo = s0 ? -bor2 : bor2;
            pair_update(SR[u], SI[u], SR[u], SI[u], PR, PI, cmr2, coi2, eb, eo);
        }
    } else {
        // partner pair is u^px: process both jointly from saved values
#pragma unroll
        for (int u = 0; u < 8; ++u) {
            const int pu = u ^ px;
            if (u < pu) {
                const v2 XRa = SR[u],  XIa = SI[u];
                const v2 XRb = SR[pu], XIb = SI[pu];
                v2 PRa, PIa, PRb, PIb;
                mk_partner<pLane, pswap>(XRb, XIb, PRa, PIa, lane4);
                mk_partner<pLane, pswap>(XRa, XIa, PRb, PIb, lane4);
                {
                    const bool s0 = (__builtin_popcount(u & rLoc) & 1) != 0;
                    const v2 eb = s0 ? -bmi2 : bmi2;
                    const v2 eo = s0 ? -bor2 : bor2;
                    pair_update(SR[u], SI[u], XRa, XIa, PRa, PIa, cmr2, coi2, eb, eo);
                }
                {
                    const bool s0 = (__builtin_popcount(pu & rLoc) & 1) != 0;
                    const v2 eb = s0 ? -bmi2 : bmi2;
                    const v2 eo = s0 ? -bor2 : bor2;
                    pair_update(SR[pu], SI[pu], XRb, XIb, PRb, PIb, cmr2, coi2, eb, eo);
                }
            }
        }
    }
}

template<int... Gs>
__device__ __forceinline__ void apply_all(v2 (&SR)[8], v2 (&SI)[8],
                                          const float4* __restrict__ rotm,
                                          int lane, int lane4,
                                          std::integer_sequence<int, Gs...>) {
    (apply_rot<Gs>(SR, SI, rotm, lane, lane4), ...);
}

__global__ __launch_bounds__(256) void vqc_kernel(const float* __restrict__ X,
                                                  const float* __restrict__ W,
                                                  const float* __restrict__ bias,
                                                  float* __restrict__ out,
                                                  int n_samples) {
    __shared__ float4 rotm[NL * NW];
    const int t = threadIdx.x;

    // per-block Rot coefficient prep: only m00, m01 needed (SU(2))
    if (t < NL * NW) {
        const float phi = W[t * 3 + 0], th = W[t * 3 + 1], om = W[t * 3 + 2];
        float sh, ch; sincosf(0.5f * th, &sh, &ch);
        float s0, c0; sincosf(-0.5f * (phi + om), &s0, &c0);   // e^{-i(phi+om)/2}
        float s1, c1; sincosf( 0.5f * (phi - om), &s1, &c1);   // e^{+i(phi-om)/2}
        rotm[t] = make_float4(c0 * ch, s0 * ch, -c1 * sh, -s1 * sh);
    }
    __syncthreads();

    const int wave = (blockIdx.x * blockDim.x + t) >> 6;   // one wave per sample
    const int lane = t & 63;
    const int lane4 = lane << 2;
    if (wave >= n_samples) return;

    // ---- product-state init: per-wire 2-vector v_w = Rot0_w * RY(x_w*pi/2)|0> ----
    const float* xp = X + wave * NW;
    float v0r[NW], v0i[NW], v1r[NW], v1i[NW];
#pragma unroll
    for (int w = 0; w < NW; ++w) {
        float s, c;
        __sincosf(xp[w] * 0.78539816339744831f, &s, &c);   // half-angle = x*pi/4
        const float4 m = rotm[w];                          // layer 0
        v0r[w] =  m.x * c + m.z * s;
        v0i[w] =  m.y * c + m.w * s;
        v1r[w] = -m.z * c + m.x * s;
        v1i[w] =  m.w * c - m.y * s;
    }
    // lane product H over wires 0..5 (wire w -> lane bit 5-w)
    float hr, hi;
    {
        const bool b0 = (lane >> 5) & 1;
        hr = b0 ? v1r[0] : v0r[0];
        hi = b0 ? v1i[0] : v0i[0];
#pragma unroll
        for (int w = 1; w < 6; ++w) {
            const bool b = (lane >> (5 - w)) & 1;
            const float br = b ? v1r[w] : v0r[w];
            const float bi = b ? v1i[w] : v0i[w];
            float nr, ni; cmul(hr, hi, br, bi, nr, ni);
            hr = nr; hi = ni;
        }
    }
    // local tables: A over wires 6,7 (j bits 3,2), B over wires 8,9 (j bits 1,0)
    float Ar[4], Ai[4], Br[4], Bi[4];
#pragma unroll
    for (int u = 0; u < 4; ++u) {
        const int hb = (u >> 1) & 1, lb = u & 1;
        cmul(hb ? v1r[6] : v0r[6], hb ? v1i[6] : v0i[6],
             lb ? v1r[7] : v0r[7], lb ? v1i[7] : v0i[7], Ar[u], Ai[u]);
        cmul(hb ? v1r[8] : v0r[8], hb ? v1i[8] : v0i[8],
             lb ? v1r[9] : v0r[9], lb ? v1i[9] : v0i[9], Br[u], Bi[u]);
    }
    // HA = H*A (4 cmults); packed state: SR[u] = {amp(u), amp(u+8)}
    float HAr[4], HAi[4];
#pragma unroll
    for (int u = 0; u < 4; ++u) cmul(hr, hi, Ar[u], Ai[u], HAr[u], HAi[u]);

    v2 SR[8], SI[8];
#pragma unroll
    for (int u = 0; u < 8; ++u) {
        float r0, i0, r1, i1;
        cmul(HAr[u >> 2],       HAi[u >> 2],       Br[u & 3], Bi[u & 3], r0, i0);
        cmul(HAr[(u >> 2) + 2], HAi[(u >> 2) + 2], Br[u & 3], Bi[u & 3], r1, i1);
        SR[u] = mkv2(r0, r1);
        SI[u] = mkv2(i0, i1);
    }

    // ---- 22 surviving rotations (layers 1..3); CNOTs are index-map updates ----
    apply_all(SR, SI, rotm, lane, lane4, std::make_integer_sequence<int, NROT>{});

    // ---- measurement: sign = parity(j_full & measmask), packed halves ----
    constexpr unsigned mm = PL.measmask;
    constexpr int mLoc = mm & 15, mLane = (int)(mm >> 4);
    v2 av = mkv2(0.0f, 0.0f);
#pragma unroll
    for (int u = 0; u < 8; ++u) {
        v2 p = SR[u] * SR[u] + SI[u] * SI[u];
        if constexpr ((mLoc & 8) != 0) p.y = -p.y;         // half-1 extra parity bit
        if (__builtin_popcount(u & mLoc & 7) & 1) av -= p; else av += p;
    }
    float acc = av.x + av.y;
    if (__popc(lane & mLane) & 1) acc = -acc;
    acc += swz<32>(acc, lane4);
    acc += swz<16>(acc, lane4);
    acc += swz<8>(acc, lane4);
    acc += swz<4>(acc, lane4);
    acc += swz<2>(acc, lane4);
    acc += swz<1>(acc, lane4);
    if (lane == 0) out[wave] = acc + bias[0];
}

extern "C" void kernel_launch(void* const* d_in, const int* in_sizes, int n_in,
                              void* d_out, int out_size, void* d_ws, size_t ws_size,
                              hipStream_t stream) {
    const float* X    = (const float*)d_in[0];
    const float* W    = (const float*)d_in[1];
    const float* bias = (const float*)d_in[2];
    float* out = (float*)d_out;
    const int n_samples = in_sizes[0] / NW;               // 16384
    const int threads = 256;                              // 4 waves/block
    const int blocks = (n_samples * 64 + threads - 1) / threads;
    hipLaunchKernelGGL(vqc_kernel, dim3(blocks), dim3(threads), 0, stream,
                       X, W, bias, out, n_samples);
}

// Round 6
// 131.657 us; speedup vs baseline: 1.0261x; 1.0261x over previous
//
#include <hip/hip_runtime.h>
#include <cstdint>
#include <utility>

#define NW 10
#define NL 4

// ============================================================================
// Round 6:
//  - CNOT rings tracked as compile-time GF(2) index maps (round 2).
//  - Lightcone: layer3 keeps Rot{1,5,9}, layer2 drops Rot(7) (round 2).
//  - Product-state init folds encoding RYs + all layer-0 Rots (round 3).
//  - v_pk_fma_f32 packed state (slots j, j+8) (round 5).
//  - NEW: DS-pipe was the bottleneck (582 DS ops/wave ≈ 90 µs at b32
//    throughput). Cross-lane xor masks 1/2/3 (quad_perm), 7 (row_half_mirror),
//    15 (row_mirror) now run as v_mov_b32_dpp on the VALU pipe -> 6 of 18
//    cross gates leave the DS pipe (582 -> ~390 DS ops/wave).
// ============================================================================

typedef float v2 __attribute__((ext_vector_type(2)));

struct Plan {
    int n;
    uint16_t pmask[40];
    uint16_t rmask[40];
    uint8_t  lw[40];
    uint16_t measmask;
};

constexpr bool keep_rot(int l, int w) {
    if (l <= 1) return true;
    if (l == 2) return w != 7;
    return w == 1 || w == 5 || w == 9;   // l == 3
}

constexpr Plan make_plan() {
    Plan P{};
    unsigned row[10], cI[10];
    for (int b = 0; b < 10; ++b) { row[b] = 1u << b; cI[b] = 1u << b; }
    P.n = 0;
    for (int l = 0; l < NL; ++l) {
        for (int w = 0; w < NW; ++w) {
            if (l > 0 && keep_rot(l, w)) {          // layer-0 Rots folded into init
                const int b = 9 - w;                // wire w = state bit 9-w
                P.pmask[P.n] = (uint16_t)cI[b];
                P.rmask[P.n] = (uint16_t)row[b];
                P.lw[P.n]    = (uint8_t)(l * NW + w);
                P.n++;
            }
        }
        const int r = l % (NW - 1) + 1;
        for (int w = 0; w < NW; ++w) {              // ring: CNOT(w, (w+r)%10)
            const int cb = 9 - w, tb = 9 - ((w + r) % NW);
            row[tb] ^= row[cb];                     // M <- C * M
            cI[cb]  ^= cI[tb];                      // Minv <- Minv * C
        }
    }
    P.measmask = (uint16_t)row[0];                  // Z on virtual bit 0 (wire 9)
    return P;
}

constexpr Plan PL = make_plan();
constexpr int NROT = 22;
static_assert(PL.n == NROT, "plan size mismatch");

__device__ __forceinline__ v2 mkv2(float a, float b) { v2 r; r.x = a; r.y = b; return r; }

// cross-lane xor exchange on one 32-bit value.
// DPP (VALU pipe) for masks 1,2,3 (quad_perm), 7 (row_half_mirror),
// 15 (row_mirror); ds_swizzle for other masks <32; ds_bpermute for >=32.
template<int MASK>
__device__ __forceinline__ float swz(float v, int lane4 /* lane<<2 */) {
    if constexpr (MASK == 1) {        // quad_perm [1,0,3,2]
        return __int_as_float(__builtin_amdgcn_mov_dpp(__float_as_int(v), 0xB1, 0xF, 0xF, true));
    } else if constexpr (MASK == 2) { // quad_perm [2,3,0,1]
        return __int_as_float(__builtin_amdgcn_mov_dpp(__float_as_int(v), 0x4E, 0xF, 0xF, true));
    } else if constexpr (MASK == 3) { // quad_perm [3,2,1,0]
        return __int_as_float(__builtin_amdgcn_mov_dpp(__float_as_int(v), 0x1B, 0xF, 0xF, true));
    } else if constexpr (MASK == 7) { // row_half_mirror
        return __int_as_float(__builtin_amdgcn_mov_dpp(__float_as_int(v), 0x141, 0xF, 0xF, true));
    } else if constexpr (MASK == 15) { // row_mirror
        return __int_as_float(__builtin_amdgcn_mov_dpp(__float_as_int(v), 0x140, 0xF, 0xF, true));
    } else if constexpr (MASK < 32) {
        return __int_as_float(__builtin_amdgcn_ds_swizzle(
            __float_as_int(v), (MASK << 10) | 0x1F));       // bit-mode xor pattern
    } else {
        return __int_as_float(__builtin_amdgcn_ds_bpermute(
            lane4 ^ (MASK << 2), __float_as_int(v)));
    }
}

// build packed partner (PR,PI) from a source pair's regs; pswap = pLoc bit3
template<int pLane, bool pswap>
__device__ __forceinline__ void mk_partner(v2 qr, v2 qi, v2& PR, v2& PI, int lane4) {
    if constexpr (pLane != 0) {
        const float rx = swz<pLane>(qr.x, lane4);
        const float ry = swz<pLane>(qr.y, lane4);
        const float ix = swz<pLane>(qi.x, lane4);
        const float iy = swz<pLane>(qi.y, lane4);
        if constexpr (pswap) { PR = mkv2(ry, rx); PI = mkv2(iy, ix); }
        else                 { PR = mkv2(rx, ry); PI = mkv2(ix, iy); }
    } else {
        if constexpr (pswap) { PR = mkv2(qr.y, qr.x); PI = mkv2(qi.y, qi.x); }
        else                 { PR = qr;               PI = qi;               }
    }
}

// packed rotation core: out = U * (X, P) with per-half signs already in eb/eo
__device__ __forceinline__ void pair_update(v2& OR_, v2& OI_, v2 XR, v2 XI, v2 PR, v2 PI,
                                            v2 cmr2, v2 coi2, v2 eb, v2 eo) {
    OR_ = cmr2 * XR - coi2 * PI - eb * XI + eo * PR;
    OI_ = cmr2 * XI + coi2 * PR + eb * XR + eo * PI;
}

__device__ __forceinline__ void cmul(float ar, float ai, float br, float bi,
                                     float& cr, float& ci) {
    cr = ar * br - ai * bi;
    ci = ar * bi + ai * br;
}

// one masked-pair rotation; SU(2): u11=conj(u00), u10=-conj(u01).
// state: SR[u]/SI[u] hold slots (u, u|8) packed.
template<int G>
__device__ __forceinline__ void apply_rot(v2 (&SR)[8], v2 (&SI)[8],
                                          const float4* __restrict__ rotm,
                                          int lane, int lane4) {
    constexpr unsigned pm = PL.pmask[G], rm = PL.rmask[G];
    constexpr int pLoc = pm & 15, pLane = (int)(pm >> 4);
    constexpr int rLoc = rm & 15, rLane = (int)(rm >> 4);
    constexpr bool pswap = (pLoc & 8) != 0;
    constexpr int  px    = pLoc & 7;
    constexpr bool mixed = (rLoc & 8) != 0;        // halves of a pair differ in role

    const float4 m = rotm[PL.lw[G]];
    const bool rl = (__popc(lane & rLane) & 1) != 0;   // runtime lane role
    const float bmi = rl ? -m.y : m.y;
    const float bor = rl ? -m.z : m.z;
    const v2 cmr2 = mkv2(m.x, m.x);
    const v2 coi2 = mkv2(m.w, m.w);
    const v2 bmi2 = mixed ? mkv2(bmi, -bmi) : mkv2(bmi, bmi);
    const v2 bor2 = mixed ? mkv2(bor, -bor) : mkv2(bor, bor);

    if constexpr (px == 0) {
        // partner lives in the same packed pair (other lane and/or other half)
#pragma unroll
        for (int u = 0; u < 8; ++u) {
            v2 PR, PI;
            mk_partner<pLane, pswap>(SR[u], SI[u], PR, PI, lane4);
            const bool s0 = (__builtin_popcount(u & rLoc) & 1) != 0;
            const v2 eb = s0 ? -bmi2 : bmi2;
            const v2 eo = s0 ? -bor2 : bor2;
            pair_update(SR[u], SI[u], SR[u], SI[u], PR, PI, cmr2, coi2, eb, eo);
        }
    } else {
        // partner pair is u^px: process both jointly from saved values
#pragma unroll
        for (int u = 0; u < 8; ++u) {
            const int pu = u ^ px;
            if (u < pu) {
                const v2 XRa = SR[u],  XIa = SI[u];
                const v2 XRb = SR[pu], XIb = SI[pu];
                v2 PRa, PIa, PRb, PIb;
                mk_partner<pLane, pswap>(XRb, XIb, PRa, PIa, lane4);
                mk_partner<pLane, pswap>(XRa, XIa, PRb, PIb, lane4);
                {
                    const bool s0 = (__builtin_popcount(u & rLoc) & 1) != 0;
                    const v2 eb = s0 ? -bmi2 : bmi2;
                    const v2 eo = s0 ? -bor2 : bor2;
                    pair_update(SR[u], SI[u], XRa, XIa, PRa, PIa, cmr2, coi2, eb, eo);
                }
                {
                    const bool s0 = (__builtin_popcount(pu & rLoc) & 1) != 0;
                    const v2 eb = s0 ? -bmi2 : bmi2;
                    const v2 eo = s0 ? -bor2 : bor2;
                    pair_update(SR[pu], SI[pu], XRb, XIb, PRb, PIb, cmr2, coi2, eb, eo);
                }
            }
        }
    }
}

template<int... Gs>
__device__ __forceinline__ void apply_all(v2 (&SR)[8], v2 (&SI)[8],
                                          const float4* __restrict__ rotm,
                                          int lane, int lane4,
                                          std::integer_sequence<int, Gs...>) {
    (apply_rot<Gs>(SR, SI, rotm, lane, lane4), ...);
}

__global__ __launch_bounds__(256) void vqc_kernel(const float* __restrict__ X,
                                                  const float* __restrict__ W,
                                                  const float* __restrict__ bias,
                                                  float* __restrict__ out,
                                                  int n_samples) {
    __shared__ float4 rotm[NL * NW];
    const int t = threadIdx.x;

    // per-block Rot coefficient prep: only m00, m01 needed (SU(2))
    if (t < NL * NW) {
        const float phi = W[t * 3 + 0], th = W[t * 3 + 1], om = W[t * 3 + 2];
        float sh, ch; sincosf(0.5f * th, &sh, &ch);
        float s0, c0; sincosf(-0.5f * (phi + om), &s0, &c0);   // e^{-i(phi+om)/2}
        float s1, c1; sincosf( 0.5f * (phi - om), &s1, &c1);   // e^{+i(phi-om)/2}
        rotm[t] = make_float4(c0 * ch, s0 * ch, -c1 * sh, -s1 * sh);
    }
    __syncthreads();

    const int wave = (blockIdx.x * blockDim.x + t) >> 6;   // one wave per sample
    const int lane = t & 63;
    const int lane4 = lane << 2;
    if (wave >= n_samples) return;

    // ---- product-state init: per-wire 2-vector v_w = Rot0_w * RY(x_w*pi/2)|0> ----
    const float* xp = X + wave * NW;
    float v0r[NW], v0i[NW], v1r[NW], v1i[NW];
#pragma unroll
    for (int w = 0; w < NW; ++w) {
        float s, c;
        __sincosf(xp[w] * 0.78539816339744831f, &s, &c);   // half-angle = x*pi/4
        const float4 m = rotm[w];                          // layer 0
        v0r[w] =  m.x * c + m.z * s;
        v0i[w] =  m.y * c + m.w * s;
        v1r[w] = -m.z * c + m.x * s;
        v1i[w] =  m.w * c - m.y * s;
    }
    // lane product H over wires 0..5 (wire w -> lane bit 5-w)
    float hr, hi;
    {
        const bool b0 = (lane >> 5) & 1;
        hr = b0 ? v1r[0] : v0r[0];
        hi = b0 ? v1i[0] : v0i[0];
#pragma unroll
        for (int w = 1; w < 6; ++w) {
            const bool b = (lane >> (5 - w)) & 1;
            const float br = b ? v1r[w] : v0r[w];
            const float bi = b ? v1i[w] : v0i[w];
            float nr, ni; cmul(hr, hi, br, bi, nr, ni);
            hr = nr; hi = ni;
        }
    }
    // local tables: A over wires 6,7 (j bits 3,2), B over wires 8,9 (j bits 1,0)
    float Ar[4], Ai[4], Br[4], Bi[4];
#pragma unroll
    for (int u = 0; u < 4; ++u) {
        const int hb = (u >> 1) & 1, lb = u & 1;
        cmul(hb ? v1r[6] : v0r[6], hb ? v1i[6] : v0i[6],
             lb ? v1r[7] : v0r[7], lb ? v1i[7] : v0i[7], Ar[u], Ai[u]);
        cmul(hb ? v1r[8] : v0r[8], hb ? v1i[8] : v0i[8],
             lb ? v1r[9] : v0r[9], lb ? v1i[9] : v0i[9], Br[u], Bi[u]);
    }
    // HA = H*A (4 cmults); packed state: SR[u] = {amp(u), amp(u+8)}
    float HAr[4], HAi[4];
#pragma unroll
    for (int u = 0; u < 4; ++u) cmul(hr, hi, Ar[u], Ai[u], HAr[u], HAi[u]);

    v2 SR[8], SI[8];
#pragma unroll
    for (int u = 0; u < 8; ++u) {
        float r0, i0, r1, i1;
        cmul(HAr[u >> 2],       HAi[u >> 2],       Br[u & 3], Bi[u & 3], r0, i0);
        cmul(HAr[(u >> 2) + 2], HAi[(u >> 2) + 2], Br[u & 3], Bi[u & 3], r1, i1);
        SR[u] = mkv2(r0, r1);
        SI[u] = mkv2(i0, i1);
    }

    // ---- 22 surviving rotations (layers 1..3); CNOTs are index-map updates ----
    apply_all(SR, SI, rotm, lane, lane4, std::make_integer_sequence<int, NROT>{});

    // ---- measurement: sign = parity(j_full & measmask), packed halves ----
    constexpr unsigned mm = PL.measmask;
    constexpr int mLoc = mm & 15, mLane = (int)(mm >> 4);
    v2 av = mkv2(0.0f, 0.0f);
#pragma unroll
    for (int u = 0; u < 8; ++u) {
        v2 p = SR[u] * SR[u] + SI[u] * SI[u];
        if constexpr ((mLoc & 8) != 0) p.y = -p.y;         // half-1 extra parity bit
        if (__builtin_popcount(u & mLoc & 7) & 1) av -= p; else av += p;
    }
    float acc = av.x + av.y;
    if (__popc(lane & mLane) & 1) acc = -acc;
    acc += swz<32>(acc, lane4);
    acc += swz<16>(acc, lane4);
    acc += swz<8>(acc, lane4);
    acc += swz<4>(acc, lane4);
    acc += swz<2>(acc, lane4);
    acc += swz<1>(acc, lane4);
    if (lane == 0) out[wave] = acc + bias[0];
}

extern "C" void kernel_launch(void* const* d_in, const int* in_sizes, int n_in,
                              void* d_out, int out_size, void* d_ws, size_t ws_size,
                              hipStream_t stream) {
    const float* X    = (const float*)d_in[0];
    const float* W    = (const float*)d_in[1];
    const float* bias = (const float*)d_in[2];
    float* out = (float*)d_out;
    const int n_samples = in_sizes[0] / NW;               // 16384
    const int threads = 256;                              // 4 waves/block
    const int blocks = (n_samples * 64 + threads - 1) / threads;
    hipLaunchKernelGGL(vqc_kernel, dim3(blocks), dim3(threads), 0, stream,
                       X, W, bias, out, n_samples);
}

// Round 7
// 129.826 us; speedup vs baseline: 1.0405x; 1.0141x over previous
//
#include <hip/hip_runtime.h>
#include <cstdint>
#include <utility>

#define NW 10
#define NL 4

// ============================================================================
// Round 7:
//  - CNOT rings tracked as compile-time GF(2) index maps (round 2).
//  - Lightcone: layer3 keeps Rot{1,5,9}, layer2 drops Rot(7) (round 2).
//  - Product-state init folds encoding RYs + all layer-0 Rots (round 3).
//  - ds_swizzle / ds_bpermute / DPP cross-lane exchange (rounds 4,6).
//  - NEW: v2 packing axis changed from slot-pairs (j,j+8) to SAMPLE pairs:
//    each wave simulates 2 samples, v2 = {s0_amp, s1_amp}. Both halves share
//    identical gate structure -> no pswap/mixed repacking, scalar coefficients
//    fold into FMA modifiers, per-gate setup amortized 2x, wave count halved.
//    State = 16 slots x (re,im) x v2 = 64 VGPRs.
// ============================================================================

typedef float v2 __attribute__((ext_vector_type(2)));

struct Plan {
    int n;
    uint16_t pmask[40];
    uint16_t rmask[40];
    uint8_t  lw[40];
    uint16_t measmask;
};

constexpr bool keep_rot(int l, int w) {
    if (l <= 1) return true;
    if (l == 2) return w != 7;
    return w == 1 || w == 5 || w == 9;   // l == 3
}

constexpr Plan make_plan() {
    Plan P{};
    unsigned row[10], cI[10];
    for (int b = 0; b < 10; ++b) { row[b] = 1u << b; cI[b] = 1u << b; }
    P.n = 0;
    for (int l = 0; l < NL; ++l) {
        for (int w = 0; w < NW; ++w) {
            if (l > 0 && keep_rot(l, w)) {          // layer-0 Rots folded into init
                const int b = 9 - w;                // wire w = state bit 9-w
                P.pmask[P.n] = (uint16_t)cI[b];
                P.rmask[P.n] = (uint16_t)row[b];
                P.lw[P.n]    = (uint8_t)(l * NW + w);
                P.n++;
            }
        }
        const int r = l % (NW - 1) + 1;
        for (int w = 0; w < NW; ++w) {              // ring: CNOT(w, (w+r)%10)
            const int cb = 9 - w, tb = 9 - ((w + r) % NW);
            row[tb] ^= row[cb];                     // M <- C * M
            cI[cb]  ^= cI[tb];                      // Minv <- Minv * C
        }
    }
    P.measmask = (uint16_t)row[0];                  // Z on virtual bit 0 (wire 9)
    return P;
}

constexpr Plan PL = make_plan();
constexpr int NROT = 22;
static_assert(PL.n == NROT, "plan size mismatch");

// cross-lane xor exchange on one 32-bit value.
// DPP (VALU pipe) for masks 1,2,3 (quad_perm), 7 (row_half_mirror),
// 15 (row_mirror); ds_swizzle for other masks <32; ds_bpermute for >=32.
template<int MASK>
__device__ __forceinline__ float swz(float v, int lane4 /* lane<<2 */) {
    if constexpr (MASK == 1) {        // quad_perm [1,0,3,2]
        return __int_as_float(__builtin_amdgcn_mov_dpp(__float_as_int(v), 0xB1, 0xF, 0xF, true));
    } else if constexpr (MASK == 2) { // quad_perm [2,3,0,1]
        return __int_as_float(__builtin_amdgcn_mov_dpp(__float_as_int(v), 0x4E, 0xF, 0xF, true));
    } else if constexpr (MASK == 3) { // quad_perm [3,2,1,0]
        return __int_as_float(__builtin_amdgcn_mov_dpp(__float_as_int(v), 0x1B, 0xF, 0xF, true));
    } else if constexpr (MASK == 7) { // row_half_mirror
        return __int_as_float(__builtin_amdgcn_mov_dpp(__float_as_int(v), 0x141, 0xF, 0xF, true));
    } else if constexpr (MASK == 15) { // row_mirror
        return __int_as_float(__builtin_amdgcn_mov_dpp(__float_as_int(v), 0x140, 0xF, 0xF, true));
    } else if constexpr (MASK < 32) {
        return __int_as_float(__builtin_amdgcn_ds_swizzle(
            __float_as_int(v), (MASK << 10) | 0x1F));       // bit-mode xor pattern
    } else {
        return __int_as_float(__builtin_amdgcn_ds_bpermute(
            lane4 ^ (MASK << 2), __float_as_int(v)));
    }
}

template<int MASK>
__device__ __forceinline__ v2 swz2(v2 v, int lane4) {
    v2 r;
    r.x = swz<MASK>(v.x, lane4);
    r.y = swz<MASK>(v.y, lane4);
    return r;
}

__device__ __forceinline__ v2 mkv2(float a, float b) { v2 r; r.x = a; r.y = b; return r; }

__device__ __forceinline__ void cmul2(v2 ar, v2 ai, v2 br, v2 bi, v2& cr, v2& ci) {
    cr = ar * br - ai * bi;
    ci = ar * bi + ai * br;
}

// single amplitude-pair update; S (slot-role parity) folds at compile time
// after unrolling. bmi/bor already carry the lane-role sign.
__device__ __forceinline__ void upd(v2& xr, v2& xi, v2 pr, v2 pi,
                                    float cmr, float coi, float bmi, float bor,
                                    bool S) {
    const float emi = S ? -bmi : bmi;
    const float eor = S ? -bor : bor;
    const v2 nr = cmr * xr - emi * xi + eor * pr - coi * pi;
    const v2 ni = cmr * xi + emi * xr + eor * pi + coi * pr;
    xr = nr; xi = ni;
}

// one masked-pair rotation; SU(2): u11=conj(u00), u10=-conj(u01).
// state: sr[j]/si[j] = v2{sample0, sample1} for local slot j.
template<int G>
__device__ __forceinline__ void apply_rot(v2 (&sr)[16], v2 (&si)[16],
                                          const float4* __restrict__ rotm,
                                          int lane, int lane4) {
    constexpr unsigned pm = PL.pmask[G], rm = PL.rmask[G];
    constexpr int pLoc = pm & 15, pLane = (int)(pm >> 4);
    constexpr int rLoc = rm & 15, rLane = (int)(rm >> 4);
    const float4 m = rotm[PL.lw[G]];
    const bool rl = (__popc(lane & rLane) & 1) != 0;   // lane part of role
    const float cmr = m.x, coi = m.w;
    const float bmi = rl ? -m.y : m.y;
    const float bor = rl ? -m.z : m.z;

    if constexpr (pLane == 0) {
        // fully local pair (j, j^pLoc)
#pragma unroll
        for (int j = 0; j < 16; ++j) {
            const int k = j ^ pLoc;
            if (j < k) {
                const v2 ajr = sr[j], aji = si[j];
                const v2 akr = sr[k], aki = si[k];
                upd(sr[j], si[j], akr, aki, cmr, coi, bmi, bor,
                    (__builtin_popcount(j & rLoc) & 1) != 0);
                upd(sr[k], si[k], ajr, aji, cmr, coi, bmi, bor,
                    (__builtin_popcount(k & rLoc) & 1) != 0);
            }
        }
    } else if constexpr (pLoc == 0) {
        // partner = same slot, other lane
#pragma unroll
        for (int j = 0; j < 16; ++j) {
            const v2 pr = swz2<pLane>(sr[j], lane4);
            const v2 pi = swz2<pLane>(si[j], lane4);
            upd(sr[j], si[j], pr, pi, cmr, coi, bmi, bor,
                (__builtin_popcount(j & rLoc) & 1) != 0);
        }
    } else {
        // partner = slot j^pLoc at lane^pLane
#pragma unroll
        for (int j = 0; j < 16; ++j) {
            const int k = j ^ pLoc;
            if (j < k) {
                const v2 pjr = swz2<pLane>(sr[k], lane4);
                const v2 pji = swz2<pLane>(si[k], lane4);
                const v2 pkr = swz2<pLane>(sr[j], lane4);
                const v2 pki = swz2<pLane>(si[j], lane4);
                upd(sr[j], si[j], pjr, pji, cmr, coi, bmi, bor,
                    (__builtin_popcount(j & rLoc) & 1) != 0);
                upd(sr[k], si[k], pkr, pki, cmr, coi, bmi, bor,
                    (__builtin_popcount(k & rLoc) & 1) != 0);
            }
        }
    }
}

template<int... Gs>
__device__ __forceinline__ void apply_all(v2 (&sr)[16], v2 (&si)[16],
                                          const float4* __restrict__ rotm,
                                          int lane, int lane4,
                                          std::integer_sequence<int, Gs...>) {
    (apply_rot<Gs>(sr, si, rotm, lane, lane4), ...);
}

__global__ __launch_bounds__(256) void vqc_kernel(const float* __restrict__ X,
                                                  const float* __restrict__ W,
                                                  const float* __restrict__ bias,
                                                  float* __restrict__ out,
                                                  int n_pairs) {
    __shared__ float4 rotm[NL * NW];
    const int t = threadIdx.x;

    // per-block Rot coefficient prep: only m00, m01 needed (SU(2))
    if (t < NL * NW) {
        const float phi = W[t * 3 + 0], th = W[t * 3 + 1], om = W[t * 3 + 2];
        float sh, ch; sincosf(0.5f * th, &sh, &ch);
        float s0, c0; sincosf(-0.5f * (phi + om), &s0, &c0);   // e^{-i(phi+om)/2}
        float s1, c1; sincosf( 0.5f * (phi - om), &s1, &c1);   // e^{+i(phi-om)/2}
        rotm[t] = make_float4(c0 * ch, s0 * ch, -c1 * sh, -s1 * sh);
    }
    __syncthreads();

    const int wave = (blockIdx.x * blockDim.x + t) >> 6;   // one wave per SAMPLE PAIR
    const int lane = t & 63;
    const int lane4 = lane << 2;
    if (wave >= n_pairs) return;

    // ---- product-state init for both samples: v_w = Rot0_w * RY(x_w*pi/2)|0> ----
    const float* xp = X + (size_t)(2 * wave) * NW;        // sample0; sample1 at +NW

    // running lane-product H over wires 0..5 (wire w -> lane bit 5-w)
    v2 hr, hi;
#pragma unroll
    for (int w = 0; w < 6; ++w) {
        float s0, c0, s1, c1;
        __sincosf(xp[w]      * 0.78539816339744831f, &s0, &c0);
        __sincosf(xp[w + NW] * 0.78539816339744831f, &s1, &c1);
        const v2 s = mkv2(s0, s1), c = mkv2(c0, c1);
        const float4 m = rotm[w];                          // layer 0
        const v2 a0r = m.x * c + m.z * s;
        const v2 a0i = m.y * c + m.w * s;
        const v2 a1r = m.x * s - m.z * c;
        const v2 a1i = m.w * c - m.y * s;
        const bool b = (lane >> (5 - w)) & 1;
        const v2 br = b ? a1r : a0r;
        const v2 bi = b ? a1i : a0i;
        if (w == 0) { hr = br; hi = bi; }
        else {
            v2 nr, ni; cmul2(hr, hi, br, bi, nr, ni);
            hr = nr; hi = ni;
        }
    }
    // wires 6..9 kept for local tables
    v2 t0r[4], t0i[4], t1r[4], t1i[4];
#pragma unroll
    for (int w = 6; w < 10; ++w) {
        float s0, c0, s1, c1;
        __sincosf(xp[w]      * 0.78539816339744831f, &s0, &c0);
        __sincosf(xp[w + NW] * 0.78539816339744831f, &s1, &c1);
        const v2 s = mkv2(s0, s1), c = mkv2(c0, c1);
        const float4 m = rotm[w];
        t0r[w - 6] = m.x * c + m.z * s;
        t0i[w - 6] = m.y * c + m.w * s;
        t1r[w - 6] = m.x * s - m.z * c;
        t1i[w - 6] = m.w * c - m.y * s;
    }
    // A over wires 6,7 (j bits 3,2), B over wires 8,9 (j bits 1,0)
    v2 Ar[4], Ai[4], Br[4], Bi[4];
#pragma unroll
    for (int u = 0; u < 4; ++u) {
        const int hb = (u >> 1) & 1, lb = u & 1;
        cmul2(hb ? t1r[0] : t0r[0], hb ? t1i[0] : t0i[0],
              lb ? t1r[1] : t0r[1], lb ? t1i[1] : t0i[1], Ar[u], Ai[u]);
        cmul2(hb ? t1r[2] : t0r[2], hb ? t1i[2] : t0i[2],
              lb ? t1r[3] : t0r[3], lb ? t1i[3] : t0i[3], Br[u], Bi[u]);
    }
    // HA = H*A, then state[j] = HA[j>>2] * B[j&3]
    v2 HAr[4], HAi[4];
#pragma unroll
    for (int u = 0; u < 4; ++u) cmul2(hr, hi, Ar[u], Ai[u], HAr[u], HAi[u]);

    v2 sr[16], si[16];
#pragma unroll
    for (int j = 0; j < 16; ++j) {
        cmul2(HAr[j >> 2], HAi[j >> 2], Br[j & 3], Bi[j & 3], sr[j], si[j]);
    }

    // ---- 22 surviving rotations (layers 1..3); CNOTs are index-map updates ----
    apply_all(sr, si, rotm, lane, lane4, std::make_integer_sequence<int, NROT>{});

    // ---- measurement: sign = parity(j_full & measmask) ----
    constexpr unsigned mm = PL.measmask;
    constexpr int mLoc = mm & 15, mLane = (int)(mm >> 4);
    v2 acc = mkv2(0.0f, 0.0f);
#pragma unroll
    for (int j = 0; j < 16; ++j) {
        const v2 p = sr[j] * sr[j] + si[j] * si[j];
        if (__builtin_popcount(j & mLoc) & 1) acc -= p; else acc += p;
    }
    if (__popc(lane & mLane) & 1) acc = -acc;
    acc += swz2<1>(acc, lane4);
    acc += swz2<2>(acc, lane4);
    acc += swz2<4>(acc, lane4);
    acc += swz2<8>(acc, lane4);
    acc += swz2<16>(acc, lane4);
    acc += swz2<32>(acc, lane4);
    if (lane == 0) {
        const float b0 = bias[0];
        out[2 * wave]     = acc.x + b0;
        out[2 * wave + 1] = acc.y + b0;
    }
}

extern "C" void kernel_launch(void* const* d_in, const int* in_sizes, int n_in,
                              void* d_out, int out_size, void* d_ws, size_t ws_size,
                              hipStream_t stream) {
    const float* X    = (const float*)d_in[0];
    const float* W    = (const float*)d_in[1];
    const float* bias = (const float*)d_in[2];
    float* out = (float*)d_out;
    const int n_samples = in_sizes[0] / NW;               // 16384
    const int n_pairs = n_samples / 2;                    // 8192 (even batch)
    const int threads = 256;                              // 4 waves/block
    const int blocks = (n_pairs * 64 + threads - 1) / threads;
    hipLaunchKernelGGL(vqc_kernel, dim3(blocks), dim3(threads), 0, stream,
                       X, W, bias, out, n_pairs);
}

// Round 8
// 128.516 us; speedup vs baseline: 1.0511x; 1.0102x over previous
//
#include <hip/hip_runtime.h>
#include <cstdint>
#include <utility>

#define NW 10
#define NL 4

// ============================================================================
// Round 8:
//  - CNOT rings tracked as compile-time GF(2) index maps (round 2).
//  - Lightcone: layer3 keeps Rot{1,5,9}, layer2 drops Rot(7) (round 2).
//  - Product-state init folds encoding RYs + all layer-0 Rots (round 3).
//  - ds_swizzle / ds_bpermute / DPP cross-lane exchange (rounds 4,6).
//  - Sample-pair v2 packing: wave simulates 2 samples (round 7).
//  - NEW: __launch_bounds__(256, 4) -> 128-reg budget. Round 7's regression
//    was the allocator targeting high occupancy (60 VGPR) and spilling the
//    64-reg state into AGPRs (accvgpr churn, occupancy 40%, VALUBusy 44%).
//    4 waves/SIMD with the state truly register-resident is the design point.
// ============================================================================

typedef float v2 __attribute__((ext_vector_type(2)));

struct Plan {
    int n;
    uint16_t pmask[40];
    uint16_t rmask[40];
    uint8_t  lw[40];
    uint16_t measmask;
};

constexpr bool keep_rot(int l, int w) {
    if (l <= 1) return true;
    if (l == 2) return w != 7;
    return w == 1 || w == 5 || w == 9;   // l == 3
}

constexpr Plan make_plan() {
    Plan P{};
    unsigned row[10], cI[10];
    for (int b = 0; b < 10; ++b) { row[b] = 1u << b; cI[b] = 1u << b; }
    P.n = 0;
    for (int l = 0; l < NL; ++l) {
        for (int w = 0; w < NW; ++w) {
            if (l > 0 && keep_rot(l, w)) {          // layer-0 Rots folded into init
                const int b = 9 - w;                // wire w = state bit 9-w
                P.pmask[P.n] = (uint16_t)cI[b];
                P.rmask[P.n] = (uint16_t)row[b];
                P.lw[P.n]    = (uint8_t)(l * NW + w);
                P.n++;
            }
        }
        const int r = l % (NW - 1) + 1;
        for (int w = 0; w < NW; ++w) {              // ring: CNOT(w, (w+r)%10)
            const int cb = 9 - w, tb = 9 - ((w + r) % NW);
            row[tb] ^= row[cb];                     // M <- C * M
            cI[cb]  ^= cI[tb];                      // Minv <- Minv * C
        }
    }
    P.measmask = (uint16_t)row[0];                  // Z on virtual bit 0 (wire 9)
    return P;
}

constexpr Plan PL = make_plan();
constexpr int NROT = 22;
static_assert(PL.n == NROT, "plan size mismatch");

// cross-lane xor exchange on one 32-bit value.
// DPP (VALU pipe) for masks 1,2,3 (quad_perm), 7 (row_half_mirror),
// 15 (row_mirror); ds_swizzle for other masks <32; ds_bpermute for >=32.
template<int MASK>
__device__ __forceinline__ float swz(float v, int lane4 /* lane<<2 */) {
    if constexpr (MASK == 1) {        // quad_perm [1,0,3,2]
        return __int_as_float(__builtin_amdgcn_mov_dpp(__float_as_int(v), 0xB1, 0xF, 0xF, true));
    } else if constexpr (MASK == 2) { // quad_perm [2,3,0,1]
        return __int_as_float(__builtin_amdgcn_mov_dpp(__float_as_int(v), 0x4E, 0xF, 0xF, true));
    } else if constexpr (MASK == 3) { // quad_perm [3,2,1,0]
        return __int_as_float(__builtin_amdgcn_mov_dpp(__float_as_int(v), 0x1B, 0xF, 0xF, true));
    } else if constexpr (MASK == 7) { // row_half_mirror
        return __int_as_float(__builtin_amdgcn_mov_dpp(__float_as_int(v), 0x141, 0xF, 0xF, true));
    } else if constexpr (MASK == 15) { // row_mirror
        return __int_as_float(__builtin_amdgcn_mov_dpp(__float_as_int(v), 0x140, 0xF, 0xF, true));
    } else if constexpr (MASK < 32) {
        return __int_as_float(__builtin_amdgcn_ds_swizzle(
            __float_as_int(v), (MASK << 10) | 0x1F));       // bit-mode xor pattern
    } else {
        return __int_as_float(__builtin_amdgcn_ds_bpermute(
            lane4 ^ (MASK << 2), __float_as_int(v)));
    }
}

template<int MASK>
__device__ __forceinline__ v2 swz2(v2 v, int lane4) {
    v2 r;
    r.x = swz<MASK>(v.x, lane4);
    r.y = swz<MASK>(v.y, lane4);
    return r;
}

__device__ __forceinline__ v2 mkv2(float a, float b) { v2 r; r.x = a; r.y = b; return r; }

__device__ __forceinline__ void cmul2(v2 ar, v2 ai, v2 br, v2 bi, v2& cr, v2& ci) {
    cr = ar * br - ai * bi;
    ci = ar * bi + ai * br;
}

// single amplitude-pair update; S (slot-role parity) folds at compile time
// after unrolling. bmi/bor already carry the lane-role sign.
__device__ __forceinline__ void upd(v2& xr, v2& xi, v2 pr, v2 pi,
                                    float cmr, float coi, float bmi, float bor,
                                    bool S) {
    const float emi = S ? -bmi : bmi;
    const float eor = S ? -bor : bor;
    const v2 nr = cmr * xr - emi * xi + eor * pr - coi * pi;
    const v2 ni = cmr * xi + emi * xr + eor * pi + coi * pr;
    xr = nr; xi = ni;
}

// one masked-pair rotation; SU(2): u11=conj(u00), u10=-conj(u01).
// state: sr[j]/si[j] = v2{sample0, sample1} for local slot j.
template<int G>
__device__ __forceinline__ void apply_rot(v2 (&sr)[16], v2 (&si)[16],
                                          const float4* __restrict__ rotm,
                                          int lane, int lane4) {
    constexpr unsigned pm = PL.pmask[G], rm = PL.rmask[G];
    constexpr int pLoc = pm & 15, pLane = (int)(pm >> 4);
    constexpr int rLoc = rm & 15, rLane = (int)(rm >> 4);
    const float4 m = rotm[PL.lw[G]];
    const bool rl = (__popc(lane & rLane) & 1) != 0;   // lane part of role
    const float cmr = m.x, coi = m.w;
    const float bmi = rl ? -m.y : m.y;
    const float bor = rl ? -m.z : m.z;

    if constexpr (pLane == 0) {
        // fully local pair (j, j^pLoc)
#pragma unroll
        for (int j = 0; j < 16; ++j) {
            const int k = j ^ pLoc;
            if (j < k) {
                const v2 ajr = sr[j], aji = si[j];
                const v2 akr = sr[k], aki = si[k];
                upd(sr[j], si[j], akr, aki, cmr, coi, bmi, bor,
                    (__builtin_popcount(j & rLoc) & 1) != 0);
                upd(sr[k], si[k], ajr, aji, cmr, coi, bmi, bor,
                    (__builtin_popcount(k & rLoc) & 1) != 0);
            }
        }
    } else if constexpr (pLoc == 0) {
        // partner = same slot, other lane
#pragma unroll
        for (int j = 0; j < 16; ++j) {
            const v2 pr = swz2<pLane>(sr[j], lane4);
            const v2 pi = swz2<pLane>(si[j], lane4);
            upd(sr[j], si[j], pr, pi, cmr, coi, bmi, bor,
                (__builtin_popcount(j & rLoc) & 1) != 0);
        }
    } else {
        // partner = slot j^pLoc at lane^pLane
#pragma unroll
        for (int j = 0; j < 16; ++j) {
            const int k = j ^ pLoc;
            if (j < k) {
                const v2 pjr = swz2<pLane>(sr[k], lane4);
                const v2 pji = swz2<pLane>(si[k], lane4);
                const v2 pkr = swz2<pLane>(sr[j], lane4);
                const v2 pki = swz2<pLane>(si[j], lane4);
                upd(sr[j], si[j], pjr, pji, cmr, coi, bmi, bor,
                    (__builtin_popcount(j & rLoc) & 1) != 0);
                upd(sr[k], si[k], pkr, pki, cmr, coi, bmi, bor,
                    (__builtin_popcount(k & rLoc) & 1) != 0);
            }
        }
    }
}

template<int... Gs>
__device__ __forceinline__ void apply_all(v2 (&sr)[16], v2 (&si)[16],
                                          const float4* __restrict__ rotm,
                                          int lane, int lane4,
                                          std::integer_sequence<int, Gs...>) {
    (apply_rot<Gs>(sr, si, rotm, lane, lane4), ...);
}

// 256 threads, min 4 waves/EU -> 128-reg budget: state stays in VGPRs,
// no AGPR spill (round 7 regression), 4 waves/SIMD for latency hiding.
__global__ __launch_bounds__(256, 4) void vqc_kernel(const float* __restrict__ X,
                                                     const float* __restrict__ W,
                                                     const float* __restrict__ bias,
                                                     float* __restrict__ out,
                                                     int n_pairs) {
    __shared__ float4 rotm[NL * NW];
    const int t = threadIdx.x;

    // per-block Rot coefficient prep: only m00, m01 needed (SU(2))
    if (t < NL * NW) {
        const float phi = W[t * 3 + 0], th = W[t * 3 + 1], om = W[t * 3 + 2];
        float sh, ch; sincosf(0.5f * th, &sh, &ch);
        float s0, c0; sincosf(-0.5f * (phi + om), &s0, &c0);   // e^{-i(phi+om)/2}
        float s1, c1; sincosf( 0.5f * (phi - om), &s1, &c1);   // e^{+i(phi-om)/2}
        rotm[t] = make_float4(c0 * ch, s0 * ch, -c1 * sh, -s1 * sh);
    }
    __syncthreads();

    const int wave = (blockIdx.x * blockDim.x + t) >> 6;   // one wave per SAMPLE PAIR
    const int lane = t & 63;
    const int lane4 = lane << 2;
    if (wave >= n_pairs) return;

    // ---- product-state init for both samples: v_w = Rot0_w * RY(x_w*pi/2)|0> ----
    const float* xp = X + (size_t)(2 * wave) * NW;        // sample0; sample1 at +NW

    // running lane-product H over wires 0..5 (wire w -> lane bit 5-w)
    v2 hr, hi;
#pragma unroll
    for (int w = 0; w < 6; ++w) {
        float s0, c0, s1, c1;
        __sincosf(xp[w]      * 0.78539816339744831f, &s0, &c0);
        __sincosf(xp[w + NW] * 0.78539816339744831f, &s1, &c1);
        const v2 s = mkv2(s0, s1), c = mkv2(c0, c1);
        const float4 m = rotm[w];                          // layer 0
        const v2 a0r = m.x * c + m.z * s;
        const v2 a0i = m.y * c + m.w * s;
        const v2 a1r = m.x * s - m.z * c;
        const v2 a1i = m.w * c - m.y * s;
        const bool b = (lane >> (5 - w)) & 1;
        const v2 br = b ? a1r : a0r;
        const v2 bi = b ? a1i : a0i;
        if (w == 0) { hr = br; hi = bi; }
        else {
            v2 nr, ni; cmul2(hr, hi, br, bi, nr, ni);
            hr = nr; hi = ni;
        }
    }
    // wires 6..9 kept for local tables
    v2 t0r[4], t0i[4], t1r[4], t1i[4];
#pragma unroll
    for (int w = 6; w < 10; ++w) {
        float s0, c0, s1, c1;
        __sincosf(xp[w]      * 0.78539816339744831f, &s0, &c0);
        __sincosf(xp[w + NW] * 0.78539816339744831f, &s1, &c1);
        const v2 s = mkv2(s0, s1), c = mkv2(c0, c1);
        const float4 m = rotm[w];
        t0r[w - 6] = m.x * c + m.z * s;
        t0i[w - 6] = m.y * c + m.w * s;
        t1r[w - 6] = m.x * s - m.z * c;
        t1i[w - 6] = m.w * c - m.y * s;
    }
    // A over wires 6,7 (j bits 3,2), B over wires 8,9 (j bits 1,0)
    v2 Ar[4], Ai[4], Br[4], Bi[4];
#pragma unroll
    for (int u = 0; u < 4; ++u) {
        const int hb = (u >> 1) & 1, lb = u & 1;
        cmul2(hb ? t1r[0] : t0r[0], hb ? t1i[0] : t0i[0],
              lb ? t1r[1] : t0r[1], lb ? t1i[1] : t0i[1], Ar[u], Ai[u]);
        cmul2(hb ? t1r[2] : t0r[2], hb ? t1i[2] : t0i[2],
              lb ? t1r[3] : t0r[3], lb ? t1i[3] : t0i[3], Br[u], Bi[u]);
    }
    // HA = H*A, then state[j] = HA[j>>2] * B[j&3]
    v2 HAr[4], HAi[4];
#pragma unroll
    for (int u = 0; u < 4; ++u) cmul2(hr, hi, Ar[u], Ai[u], HAr[u], HAi[u]);

    v2 sr[16], si[16];
#pragma unroll
    for (int j = 0; j < 16; ++j) {
        cmul2(HAr[j >> 2], HAi[j >> 2], Br[j & 3], Bi[j & 3], sr[j], si[j]);
    }

    // ---- 22 surviving rotations (layers 1..3); CNOTs are index-map updates ----
    apply_all(sr, si, rotm, lane, lane4, std::make_integer_sequence<int, NROT>{});

    // ---- measurement: sign = parity(j_full & measmask) ----
    constexpr unsigned mm = PL.measmask;
    constexpr int mLoc = mm & 15, mLane = (int)(mm >> 4);
    v2 acc = mkv2(0.0f, 0.0f);
#pragma unroll
    for (int j = 0; j < 16; ++j) {
        const v2 p = sr[j] * sr[j] + si[j] * si[j];
        if (__builtin_popcount(j & mLoc) & 1) acc -= p; else acc += p;
    }
    if (__popc(lane & mLane) & 1) acc = -acc;
    acc += swz2<1>(acc, lane4);
    acc += swz2<2>(acc, lane4);
    acc += swz2<4>(acc, lane4);
    acc += swz2<8>(acc, lane4);
    acc += swz2<16>(acc, lane4);
    acc += swz2<32>(acc, lane4);
    if (lane == 0) {
        const float b0 = bias[0];
        out[2 * wave]     = acc.x + b0;
        out[2 * wave + 1] = acc.y + b0;
    }
}

extern "C" void kernel_launch(void* const* d_in, const int* in_sizes, int n_in,
                              void* d_out, int out_size, void* d_ws, size_t ws_size,
                              hipStream_t stream) {
    const float* X    = (const float*)d_in[0];
    const float* W    = (const float*)d_in[1];
    const float* bias = (const float*)d_in[2];
    float* out = (float*)d_out;
    const int n_samples = in_sizes[0] / NW;               // 16384
    const int n_pairs = n_samples / 2;                    // 8192 (even batch)
    const int threads = 256;                              // 4 waves/block
    const int blocks = (n_pairs * 64 + threads - 1) / threads;
    hipLaunchKernelGGL(vqc_kernel, dim3(blocks), dim3(threads), 0, stream,
                       X, W, bias, out, n_pairs);
}